// Round 7
// baseline (149.001 us; speedup 1.0000x reference)
//
#include <hip/hip_runtime.h>
#include <hip/hip_cooperative_groups.h>
#include <math.h>

namespace cg = cooperative_groups;

#define D     1024
#define D4    256     // D/4
#define BI    48
#define BC    48
#define RR    36
#define TT    40
#define EPSF  1e-5f
#define PRG   208     // cap-stat row groups (blocks 0..207)
#define L2E   1.4426950408889634f

// 3-image fovea pass. 768 items total; swizzle keeps item%8 -> same b-range.
__device__ __forceinline__ void fovea_item(int item, int tid,
                                           const float4* __restrict__ cap4,
                                           const float* __restrict__ mean,
                                           const float* __restrict__ scale,
                                           const float* __restrict__ g1,
                                           const float* __restrict__ be,
                                           const float* __restrict__ img_n,
                                           float* smem,
                                           float* __restrict__ out) {
    int wg = (item & 7) * 96 + (item >> 3);  // bijective over 768
    int b = wg >> 4, ig = wg & 15;
    int i0 = ig * 3;

    float4 m4  = ((const float4*)mean)[tid];
    float4 sc4 = ((const float4*)scale)[tid];
    float mm[4] = {m4.x, m4.y, m4.z, m4.w};
    float sc[4] = {sc4.x, sc4.y, sc4.z, sc4.w};

    // G2 = g*sc*L2E ; B2 = (bt - g*sc*m)*L2E ; log2e scale cancels in l2norm
    float G2[3][4], B2[3][4];
#pragma unroll
    for (int u = 0; u < 3; ++u) {
        float4 t0 = ((const float4*)g1)[(size_t)(i0 + u) * D4 + tid];
        float4 u0 = ((const float4*)be)[(size_t)(i0 + u) * D4 + tid];
        float gg[4] = {t0.x, t0.y, t0.z, t0.w};
        float bt[4] = {u0.x, u0.y, u0.z, u0.w};
#pragma unroll
        for (int c = 0; c < 4; ++c) {
            float t = gg[c] * sc[c];
            G2[u][c] = t * L2E;
            B2[u][c] = fmaf(-t, mm[c], bt[c]) * L2E;
        }
    }
    float se[3][4], vm[3][4];
#pragma unroll
    for (int u = 0; u < 3; ++u)
#pragma unroll
        for (int c = 0; c < 4; ++c) { se[u][c] = 0.f; vm[u][c] = -INFINITY; }

#pragma unroll 2
    for (int t = 0; t < TT; ++t) {
        float4 c4 = cap4[((size_t)b * TT + t) * D4 + tid];
        float cc[4] = {c4.x, c4.y, c4.z, c4.w};
#pragma unroll
        for (int u = 0; u < 3; ++u)
#pragma unroll
            for (int c = 0; c < 4; ++c) {
                float y = fmaf(cc[c], G2[u][c], B2[u][c]);
                float e = __builtin_amdgcn_exp2f(y);
                se[u][c] += e;
                vm[u][c] = fmaxf(vm[u][c], y * e);
            }
    }
    float dd[3], sq[3];
#pragma unroll
    for (int u = 0; u < 3; ++u) {
        float4 nn = ((const float4*)img_n)[(size_t)(i0 + u) * D4 + tid];
        float n[4] = {nn.x, nn.y, nn.z, nn.w};
        float d2 = 0.f, q2 = 0.f;
#pragma unroll
        for (int c = 0; c < 4; ++c) {
            float v = vm[u][c] / se[u][c];
            q2 += v * v;
            d2 += v * n[c];
        }
        dd[u] = d2; sq[u] = q2;
    }
#pragma unroll
    for (int off = 32; off; off >>= 1) {
#pragma unroll
        for (int u = 0; u < 3; ++u) {
            dd[u] += __shfl_xor(dd[u], off, 64);
            sq[u] += __shfl_xor(sq[u], off, 64);
        }
    }
    float* rd = smem;        // 12 floats
    float* rq = smem + 16;   // 12 floats
    int wave = tid >> 6, lane = tid & 63;
    __syncthreads();                 // protect smem reuse across items/phases
    if (lane == 0) {
#pragma unroll
        for (int u = 0; u < 3; ++u) { rd[u * 4 + wave] = dd[u]; rq[u * 4 + wave] = sq[u]; }
    }
    __syncthreads();
    if (tid < 3) {
        float td = rd[tid * 4 + 0] + rd[tid * 4 + 1] + rd[tid * 4 + 2] + rd[tid * 4 + 3];
        float ts = rq[tid * 4 + 0] + rq[tid * 4 + 1] + rq[tid * 4 + 2] + rq[tid * 4 + 3];
        out[(size_t)(i0 + tid) * BC + b] = td / sqrtf(ts);
    }
}

__global__ __launch_bounds__(256, 2) void k_all(const float* __restrict__ cap,
                                                const float* __restrict__ img,
                                                const float* __restrict__ Wg,
                                                const float* __restrict__ bg,
                                                const float* __restrict__ Wb,
                                                const float* __restrict__ bb,
                                                float* __restrict__ ps,
                                                float* __restrict__ pss,
                                                float* __restrict__ img_q,
                                                float* __restrict__ img_n,
                                                float* __restrict__ g1,
                                                float* __restrict__ be,
                                                float* __restrict__ mean,
                                                float* __restrict__ scale,
                                                float* __restrict__ out) {
    __shared__ float smem[12544];            // 50176 B
    cg::grid_group grid = cg::this_grid();
    int bx = blockIdx.x, tid = threadIdx.x;
    int wave = tid >> 6, lane = tid & 63;

    // ============ Phase 1: cap BN partials (0..207) + img_q/img_n (208..255)
    if (bx < PRG) {
        const float4* cap4 = (const float4*)cap;
        int r0 = bx * 9 + (bx < 48 ? bx : 48);
        int nr = 9 + (bx < 48 ? 1 : 0);      // 48*10 + 160*9 = 1920
        float4 s = {0,0,0,0}, ss = {0,0,0,0};
        for (int r = 0; r < nr; ++r) {
            float4 v = cap4[(size_t)(r0 + r) * D4 + tid];
            s.x += v.x; s.y += v.y; s.z += v.z; s.w += v.w;
            ss.x += v.x*v.x; ss.y += v.y*v.y; ss.z += v.z*v.z; ss.w += v.w*v.w;
        }
        ((float4*)ps)[(size_t)bx * D4 + tid]  = s;
        ((float4*)pss)[(size_t)bx * D4 + tid] = ss;
    } else {
        int i = bx - PRG;                    // 0..47
        const float4* img4 = (const float4*)img;
        float4 s = {0,0,0,0};
#pragma unroll
        for (int r = 0; r < RR; ++r) {
            float4 v = img4[((size_t)i * RR + r) * D4 + tid];
            s.x += v.x; s.y += v.y; s.z += v.z; s.w += v.w;
        }
        const float inv = 1.f / 36.f;
        float4 q = {s.x*inv, s.y*inv, s.z*inv, s.w*inv};
        ((float4*)img_q)[(size_t)i * D4 + tid] = q;
        float ssq = q.x*q.x + q.y*q.y + q.z*q.z + q.w*q.w;
#pragma unroll
        for (int off = 32; off; off >>= 1) ssq += __shfl_xor(ssq, off, 64);
        if (lane == 0) smem[wave] = ssq;
        __syncthreads();
        float rinv = rsqrtf(smem[0] + smem[1] + smem[2] + smem[3]);
        float4 n = {q.x*rinv, q.y*rinv, q.z*rinv, q.w*rinv};
        ((float4*)img_n)[(size_t)i * D4 + tid] = n;
    }
    grid.sync();

    // ============ Phase 2: FiLM GEMM, 2 rows/wave (rows 0..2047) ============
    {
        float4* lq4 = (float4*)smem;
        int row0 = bx * 8 + wave * 2;        // even; pair never crosses 1024
        int isbeta = row0 >> 10;
        int d0 = row0 & 1023;                // d1 = d0 + 1
        const float4* W4 = (const float4*)(isbeta ? Wb : Wg);

        float acc[2][BI];
#pragma unroll
        for (int r = 0; r < 2; ++r)
#pragma unroll
            for (int i = 0; i < BI; ++i) acc[r][i] = 0.f;

        const float4* q4g = (const float4*)img_q;
        for (int kc = 0; kc < 4; ++kc) {
            __syncthreads();
            for (int idx = tid; idx < BI * 64; idx += 256) {
                int i = idx >> 6, kk = idx & 63;
                lq4[idx] = q4g[(size_t)i * D4 + kc * 64 + kk];
            }
            __syncthreads();
            float4 wv0 = W4[(size_t)d0 * D4 + kc * 64 + lane];
            float4 wv1 = W4[(size_t)(d0 + 1) * D4 + kc * 64 + lane];
#pragma unroll
            for (int i = 0; i < BI; ++i) {
                float4 q = lq4[i * 64 + lane];
                acc[0][i] = fmaf(wv0.x, q.x, acc[0][i]);
                acc[0][i] = fmaf(wv0.y, q.y, acc[0][i]);
                acc[0][i] = fmaf(wv0.z, q.z, acc[0][i]);
                acc[0][i] = fmaf(wv0.w, q.w, acc[0][i]);
                acc[1][i] = fmaf(wv1.x, q.x, acc[1][i]);
                acc[1][i] = fmaf(wv1.y, q.y, acc[1][i]);
                acc[1][i] = fmaf(wv1.z, q.z, acc[1][i]);
                acc[1][i] = fmaf(wv1.w, q.w, acc[1][i]);
            }
        }
        // transpose-reduce per row in wave-private LDS (stride 49); DS ops
        // within a wave are ordered, so no barrier needed between rows.
        __syncthreads();                     // all waves done reading lq4
        float* tr = smem + wave * 3136;      // 64*49 floats
        float* outp = isbeta ? be : g1;
#pragma unroll
        for (int r = 0; r < 2; ++r) {
#pragma unroll
            for (int i = 0; i < BI; ++i) tr[lane * 49 + i] = acc[r][i];
            float s0 = 0.f, s1 = 0.f, s2 = 0.f, s3 = 0.f;
#pragma unroll
            for (int l = 0; l < 64; l += 4) {
                s0 += tr[(l + 0) * 49 + lane];
                s1 += tr[(l + 1) * 49 + lane];
                s2 += tr[(l + 2) * 49 + lane];
                s3 += tr[(l + 3) * 49 + lane];
            }
            float sum = (s0 + s1) + (s2 + s3);
            int d = d0 + r;
            if (lane < BI) {
                float badd = isbeta ? bb[d] : (bg[d] + 1.f);   // store 1+gamma
                outp[(size_t)lane * D + d] = sum + badd;
            }
        }
    }
    if (bx < 8) {                            // ---- BN finalize appended
        __syncthreads();
        int c32 = tid & 31;
        int col = bx * 32 + c32;             // float4 column 0..255
        int rs  = tid >> 5;                  // 0..7 row-subsets
        const float4* ps4  = (const float4*)ps;
        const float4* pss4 = (const float4*)pss;
        float4 s = {0,0,0,0}, q = {0,0,0,0};
#pragma unroll
        for (int gi = 0; gi < PRG / 8; ++gi) {
            int rg = rs * (PRG / 8) + gi;
            float4 a  = ps4[(size_t)rg * D4 + col];
            float4 b2 = pss4[(size_t)rg * D4 + col];
            s.x += a.x;  s.y += a.y;  s.z += a.z;  s.w += a.w;
            q.x += b2.x; q.y += b2.y; q.z += b2.z; q.w += b2.w;
        }
        float4* red = (float4*)smem;
        red[rs * 32 + c32]       = s;
        red[256 + rs * 32 + c32] = q;
        __syncthreads();
        if (rs == 0) {
            float4 S = {0,0,0,0}, Q = {0,0,0,0};
#pragma unroll
            for (int r2 = 0; r2 < 8; ++r2) {
                float4 a  = red[r2 * 32 + c32];
                float4 b2 = red[256 + r2 * 32 + c32];
                S.x += a.x;  S.y += a.y;  S.z += a.z;  S.w += a.w;
                Q.x += b2.x; Q.y += b2.y; Q.z += b2.z; Q.w += b2.w;
            }
            const float inv = 1.f / 1920.f;
            float4 M = {S.x*inv, S.y*inv, S.z*inv, S.w*inv};
            float4 SC;
            SC.x = rsqrtf(Q.x*inv - M.x*M.x + EPSF);
            SC.y = rsqrtf(Q.y*inv - M.y*M.y + EPSF);
            SC.z = rsqrtf(Q.z*inv - M.z*M.z + EPSF);
            SC.w = rsqrtf(Q.w*inv - M.w*M.w + EPSF);
            ((float4*)mean)[col]  = M;
            ((float4*)scale)[col] = SC;
        }
    }
    grid.sync();

    // ============ Phase 3: fovea — 768 items = 256 blocks x 3 exactly ======
    fovea_item(bx,       tid, (const float4*)cap, mean, scale, g1, be, img_n, smem, out);
    fovea_item(bx + 256, tid, (const float4*)cap, mean, scale, g1, be, img_n, smem, out);
    fovea_item(bx + 512, tid, (const float4*)cap, mean, scale, g1, be, img_n, smem, out);
}

extern "C" void kernel_launch(void* const* d_in, const int* in_sizes, int n_in,
                              void* d_out, int out_size, void* d_ws, size_t ws_size,
                              hipStream_t stream) {
    const float* img = (const float*)d_in[0];
    const float* cap = (const float*)d_in[1];
    // d_in[2] = lens (unused)
    const float* Wg  = (const float*)d_in[3];
    const float* bg  = (const float*)d_in[4];
    const float* Wb  = (const float*)d_in[5];
    const float* bb  = (const float*)d_in[6];
    float* out = (float*)d_out;

    float* ws    = (float*)d_ws;
    float* ps    = ws;                     // 208*1024
    float* pss   = ps    + PRG * D;        // 208*1024
    float* img_q = pss   + PRG * D;        // 48*1024
    float* img_n = img_q + BI * D;         // 48*1024
    float* g1    = img_n + BI * D;         // 48*1024
    float* be    = g1    + BI * D;         // 48*1024
    float* mean  = be    + BI * D;         // 1024
    float* scale = mean  + D;              // 1024

    void* args[] = {(void*)&cap, (void*)&img, (void*)&Wg, (void*)&bg,
                    (void*)&Wb, (void*)&bb, (void*)&ps, (void*)&pss,
                    (void*)&img_q, (void*)&img_n, (void*)&g1, (void*)&be,
                    (void*)&mean, (void*)&scale, (void*)&out};
    hipLaunchCooperativeKernel((const void*)k_all, dim3(256), dim3(256),
                               args, 0, stream);
}

// Round 8
// 49.504 us; speedup vs baseline: 3.0099x; 3.0099x over previous
//
#include <hip/hip_runtime.h>
#include <math.h>

#define D     1024
#define D4    256     // D/4
#define BI    48
#define BC    48
#define RR    36
#define TT    40
#define EPSF  1e-5f
#define PRG   128     // cap-stat row groups
#define CROWS 15      // rows per group (128*15 = 1920)
#define L2E   1.4426950408889634f

typedef float f2 __attribute__((ext_vector_type(2)));

static __device__ __forceinline__ f2 f2max(f2 a, f2 b) {
    f2 r; r.x = fmaxf(a.x, b.x); r.y = fmaxf(a.y, b.y); return r;
}

// ---- K1: cap BN partial sums (blocks 0..127) + img_q/img_n (blocks 128..175)
__global__ __launch_bounds__(256) void k_stats(const float* __restrict__ cap,
                                               const float* __restrict__ img,
                                               float* __restrict__ ps,
                                               float* __restrict__ pss,
                                               float* __restrict__ img_q,
                                               float* __restrict__ img_n) {
    __shared__ float sw[4];
    int bx = blockIdx.x, tid = threadIdx.x;
    if (bx < PRG) {
        const float4* cap4 = (const float4*)cap;
        float4 s = {0,0,0,0}, ss = {0,0,0,0};
        int r0 = bx * CROWS;
#pragma unroll
        for (int r = 0; r < CROWS; ++r) {
            float4 v = cap4[(size_t)(r0 + r) * D4 + tid];
            s.x += v.x; s.y += v.y; s.z += v.z; s.w += v.w;
            ss.x += v.x*v.x; ss.y += v.y*v.y; ss.z += v.z*v.z; ss.w += v.w*v.w;
        }
        ((float4*)ps)[(size_t)bx * D4 + tid]  = s;
        ((float4*)pss)[(size_t)bx * D4 + tid] = ss;
    } else {
        int i = bx - PRG;
        const float4* img4 = (const float4*)img;
        float4 s = {0,0,0,0};
#pragma unroll
        for (int r = 0; r < RR; ++r) {
            float4 v = img4[((size_t)i * RR + r) * D4 + tid];
            s.x += v.x; s.y += v.y; s.z += v.z; s.w += v.w;
        }
        const float inv = 1.f / 36.f;
        float4 q = {s.x*inv, s.y*inv, s.z*inv, s.w*inv};
        ((float4*)img_q)[(size_t)i * D4 + tid] = q;
        float ssq = q.x*q.x + q.y*q.y + q.z*q.z + q.w*q.w;
#pragma unroll
        for (int off = 32; off; off >>= 1) ssq += __shfl_xor(ssq, off, 64);
        if ((tid & 63) == 0) sw[tid >> 6] = ssq;
        __syncthreads();
        float rinv = rsqrtf(sw[0] + sw[1] + sw[2] + sw[3]);
        float4 n = {q.x*rinv, q.y*rinv, q.z*rinv, q.w*rinv};
        ((float4*)img_n)[(size_t)i * D4 + tid] = n;
    }
}

// ---- K2: FiLM GEMMs (blocks 0..511: wave = 1 virtual row x 48 images)
//          + BN finalize (blocks 512..519). W rows prefetched upfront.
__global__ __launch_bounds__(256) void k_film(const float* __restrict__ img_q,
                                              const float* __restrict__ Wg,
                                              const float* __restrict__ bg,
                                              const float* __restrict__ Wb,
                                              const float* __restrict__ bb,
                                              const float* __restrict__ ps,
                                              const float* __restrict__ pss,
                                              float* __restrict__ g1,
                                              float* __restrict__ be,
                                              float* __restrict__ mean,
                                              float* __restrict__ scale) {
    __shared__ float smem[12544];            // 50176 B: lq4 (49152) / trbuf 4x3136
    float4* lq4 = (float4*)smem;
    int tid = threadIdx.x;

    if (blockIdx.x >= 512) {                 // ---- BN finalize: 8 blocks
        int bx2 = blockIdx.x - 512;          // 0..7
        int c32 = tid & 31;
        int col = bx2 * 32 + c32;            // float4 column 0..255
        int rs  = tid >> 5;                  // 0..7 row-subsets
        const float4* ps4  = (const float4*)ps;
        const float4* pss4 = (const float4*)pss;
        float4 s = {0,0,0,0}, q = {0,0,0,0};
#pragma unroll
        for (int gi = 0; gi < PRG / 8; ++gi) {
            int rg = rs * (PRG / 8) + gi;
            float4 a  = ps4[(size_t)rg * D4 + col];
            float4 b2 = pss4[(size_t)rg * D4 + col];
            s.x += a.x;  s.y += a.y;  s.z += a.z;  s.w += a.w;
            q.x += b2.x; q.y += b2.y; q.z += b2.z; q.w += b2.w;
        }
        float4* red = lq4;
        red[rs * 32 + c32]       = s;
        red[256 + rs * 32 + c32] = q;
        __syncthreads();
        if (rs == 0) {
            float4 S = {0,0,0,0}, Q = {0,0,0,0};
#pragma unroll
            for (int r2 = 0; r2 < 8; ++r2) {
                float4 a  = red[r2 * 32 + c32];
                float4 b2 = red[256 + r2 * 32 + c32];
                S.x += a.x;  S.y += a.y;  S.z += a.z;  S.w += a.w;
                Q.x += b2.x; Q.y += b2.y; Q.z += b2.z; Q.w += b2.w;
            }
            const float inv = 1.f / 1920.f;
            float4 M = {S.x*inv, S.y*inv, S.z*inv, S.w*inv};
            float4 SC;
            SC.x = rsqrtf(Q.x*inv - M.x*M.x + EPSF);
            SC.y = rsqrtf(Q.y*inv - M.y*M.y + EPSF);
            SC.z = rsqrtf(Q.z*inv - M.z*M.z + EPSF);
            SC.w = rsqrtf(Q.w*inv - M.w*M.w + EPSF);
            ((float4*)mean)[col]  = M;
            ((float4*)scale)[col] = SC;
        }
        return;
    }

    // ---- FiLM GEMM: wave = one virtual row (0..2047), all 48 images
    int wave = tid >> 6, lane = tid & 63;
    int row = blockIdx.x * 4 + wave;         // 0..2047
    int isbeta = row >> 10;
    int d = row & 1023;
    const float4* W4 = (const float4*)(isbeta ? Wb : Wg);

    // prefetch all 4 W chunks up front (latency overlaps kc0 staging)
    float4 wv[4];
#pragma unroll
    for (int kc = 0; kc < 4; ++kc)
        wv[kc] = W4[(size_t)d * D4 + kc * 64 + lane];

    float acc[BI];
#pragma unroll
    for (int i = 0; i < BI; ++i) acc[i] = 0.f;

    const float4* q4g = (const float4*)img_q;
#pragma unroll
    for (int kc = 0; kc < 4; ++kc) {
        __syncthreads();
        for (int idx = tid; idx < BI * 64; idx += 256) {
            int i = idx >> 6, kk = idx & 63;
            lq4[idx] = q4g[(size_t)i * D4 + kc * 64 + kk];
        }
        __syncthreads();
#pragma unroll
        for (int i = 0; i < BI; ++i) {
            float4 q = lq4[i * 64 + lane];
            acc[i] = fmaf(wv[kc].x, q.x, acc[i]);
            acc[i] = fmaf(wv[kc].y, q.y, acc[i]);
            acc[i] = fmaf(wv[kc].z, q.z, acc[i]);
            acc[i] = fmaf(wv[kc].w, q.w, acc[i]);
        }
    }
    // transpose-reduce: wave-private LDS region, stride 49 (conflict-free)
    __syncthreads();                         // all waves done reading lq4
    float* tr = smem + wave * 3136;          // 64*49 floats
#pragma unroll
    for (int i = 0; i < BI; ++i) tr[lane * 49 + i] = acc[i];
    float s0 = 0.f, s1 = 0.f, s2 = 0.f, s3 = 0.f;
#pragma unroll
    for (int l = 0; l < 64; l += 4) {
        s0 += tr[(l + 0) * 49 + lane];
        s1 += tr[(l + 1) * 49 + lane];
        s2 += tr[(l + 2) * 49 + lane];
        s3 += tr[(l + 3) * 49 + lane];
    }
    float sum = (s0 + s1) + (s2 + s3);
    if (lane < BI) {
        float badd = isbeta ? bb[d] : (bg[d] + 1.f);   // store 1+gamma
        float* outp = isbeta ? be : g1;
        outp[(size_t)lane * D + d] = sum + badd;
    }
}

// ---- K3: fused BN-normalize + Fovea + l2norm + cosine.
// 768 blocks = (b, 3 images); packed-f32 math (v_pk_*); XCD-bijective swizzle.
// log2e fold: y = x*log2e, e=2^y; vm/se carries a log2e factor (positive,
// same for all d of an (i,b) pair) -> cancels in the l2 normalization.
__global__ __launch_bounds__(256) void k_fovea(const float* __restrict__ cap,
                                               const float* __restrict__ mean,
                                               const float* __restrict__ scale,
                                               const float* __restrict__ g1,
                                               const float* __restrict__ be,
                                               const float* __restrict__ img_n,
                                               float* __restrict__ out) {
    int j = blockIdx.x;                      // 768 items
    int wg = (j & 7) * 96 + (j >> 3);        // bijective XCD swizzle (768 % 8 == 0)
    int b = wg >> 4, ig = wg & 15;
    int i0 = ig * 3;
    int tid = threadIdx.x;

    const float4* cap4 = (const float4*)cap;
    float4 m4  = ((const float4*)mean)[tid];
    float4 sc4 = ((const float4*)scale)[tid];
    f2 mm0 = {m4.x, m4.y},  mm1 = {m4.z, m4.w};
    f2 sc0 = {sc4.x, sc4.y}, sc1 = {sc4.z, sc4.w};

    // G2 = g*sc*L2E ; B2 = (bt - g*sc*m)*L2E
    f2 G2[3][2], B2[3][2];
#pragma unroll
    for (int u = 0; u < 3; ++u) {
        float4 t0 = ((const float4*)g1)[(size_t)(i0 + u) * D4 + tid];
        float4 u0 = ((const float4*)be)[(size_t)(i0 + u) * D4 + tid];
        f2 gg0 = {t0.x, t0.y}, gg1 = {t0.z, t0.w};
        f2 bt0 = {u0.x, u0.y}, bt1 = {u0.z, u0.w};
        f2 tt0 = gg0 * sc0, tt1 = gg1 * sc1;
        G2[u][0] = tt0 * L2E;
        G2[u][1] = tt1 * L2E;
        B2[u][0] = (bt0 - tt0 * mm0) * L2E;
        B2[u][1] = (bt1 - tt1 * mm1) * L2E;
    }
    f2 se[3][2], vm[3][2];
#pragma unroll
    for (int u = 0; u < 3; ++u)
#pragma unroll
        for (int c = 0; c < 2; ++c) {
            se[u][c] = (f2){0.f, 0.f};
            vm[u][c] = (f2){-INFINITY, -INFINITY};
        }

#pragma unroll 4
    for (int t = 0; t < TT; ++t) {
        float4 c4 = cap4[((size_t)b * TT + t) * D4 + tid];
        f2 cc0 = {c4.x, c4.y}, cc1 = {c4.z, c4.w};
#pragma unroll
        for (int u = 0; u < 3; ++u) {
            f2 y0 = cc0 * G2[u][0] + B2[u][0];
            f2 y1 = cc1 * G2[u][1] + B2[u][1];
            f2 e0, e1;
            e0.x = __builtin_amdgcn_exp2f(y0.x);
            e0.y = __builtin_amdgcn_exp2f(y0.y);
            e1.x = __builtin_amdgcn_exp2f(y1.x);
            e1.y = __builtin_amdgcn_exp2f(y1.y);
            se[u][0] += e0;
            se[u][1] += e1;
            vm[u][0] = f2max(vm[u][0], y0 * e0);
            vm[u][1] = f2max(vm[u][1], y1 * e1);
        }
    }
    float dd[3], sq[3];
#pragma unroll
    for (int u = 0; u < 3; ++u) {
        float4 nn = ((const float4*)img_n)[(size_t)(i0 + u) * D4 + tid];
        f2 r0, r1;
        r0.x = __builtin_amdgcn_rcpf(se[u][0].x);
        r0.y = __builtin_amdgcn_rcpf(se[u][0].y);
        r1.x = __builtin_amdgcn_rcpf(se[u][1].x);
        r1.y = __builtin_amdgcn_rcpf(se[u][1].y);
        f2 v0 = vm[u][0] * r0, v1 = vm[u][1] * r1;
        sq[u] = v0.x*v0.x + v0.y*v0.y + v1.x*v1.x + v1.y*v1.y;
        dd[u] = v0.x*nn.x + v0.y*nn.y + v1.x*nn.z + v1.y*nn.w;
    }
#pragma unroll
    for (int off = 32; off; off >>= 1) {
#pragma unroll
        for (int u = 0; u < 3; ++u) {
            dd[u] += __shfl_xor(dd[u], off, 64);
            sq[u] += __shfl_xor(sq[u], off, 64);
        }
    }
    __shared__ float rd[3][4], rq[3][4];     // [u][wave]
    int wave = tid >> 6, lane = tid & 63;
    if (lane == 0) {
#pragma unroll
        for (int u = 0; u < 3; ++u) { rd[u][wave] = dd[u]; rq[u][wave] = sq[u]; }
    }
    __syncthreads();
    if (tid < 3) {
        float td = rd[tid][0] + rd[tid][1] + rd[tid][2] + rd[tid][3];
        float ts = rq[tid][0] + rq[tid][1] + rq[tid][2] + rq[tid][3];
        out[(size_t)(i0 + tid) * BC + b] = td / sqrtf(ts);
    }
}

extern "C" void kernel_launch(void* const* d_in, const int* in_sizes, int n_in,
                              void* d_out, int out_size, void* d_ws, size_t ws_size,
                              hipStream_t stream) {
    const float* img = (const float*)d_in[0];
    const float* cap = (const float*)d_in[1];
    // d_in[2] = lens (unused)
    const float* Wg  = (const float*)d_in[3];
    const float* bg  = (const float*)d_in[4];
    const float* Wb  = (const float*)d_in[5];
    const float* bb  = (const float*)d_in[6];
    float* out = (float*)d_out;

    float* ws    = (float*)d_ws;
    float* ps    = ws;                     // 128*1024
    float* pss   = ps    + PRG * D;        // 128*1024
    float* img_q = pss   + PRG * D;        // 48*1024
    float* img_n = img_q + BI * D;         // 48*1024
    float* g1    = img_n + BI * D;         // 48*1024
    float* be    = g1    + BI * D;         // 48*1024
    float* mean  = be    + BI * D;         // 1024
    float* scale = mean  + D;              // 1024

    hipLaunchKernelGGL(k_stats, dim3(PRG + BI), dim3(256), 0, stream,
                       cap, img, ps, pss, img_q, img_n);
    hipLaunchKernelGGL(k_film,  dim3(520),      dim3(256), 0, stream,
                       img_q, Wg, bg, Wb, bb, ps, pss, g1, be, mean, scale);
    hipLaunchKernelGGL(k_fovea, dim3(768),      dim3(256), 0, stream,
                       cap, mean, scale, g1, be, img_n, out);
}